// Round 2
// baseline (1194.548 us; speedup 1.0000x reference)
//
#include <hip/hip_runtime.h>
#include <stdint.h>

#define LROWS 4240
#define ROW0 8
#define NVALID 4097

typedef float f32x4 __attribute__((ext_vector_type(4)));
typedef short bf16x8 __attribute__((ext_vector_type(8)));

__device__ __forceinline__ unsigned short f2bf(float f) {
  unsigned u = __float_as_uint(f);
  u += 0x7fffu + ((u >> 16) & 1u);
  return (unsigned short)(u >> 16);
}
__device__ __forceinline__ float bf2f(unsigned short h) {
  return __uint_as_float(((unsigned)h) << 16);
}
// OCP e4m3fn codec via exponent-shift trick (exact, incl. subnormals, RNE)
__device__ __forceinline__ uint8_t f2fp8(float f) {
  f = fminf(fmaxf(f, -448.f), 448.f);
  unsigned u = __float_as_uint(f * 0x1p-120f);
  unsigned s = (u >> 24) & 0x80u;
  u &= 0x7fffffffu;
  u += 0x7ffffu + ((u >> 20) & 1u);
  return (uint8_t)(s | (u >> 20));
}
__device__ __forceinline__ float fp82f(unsigned b) {
  return __uint_as_float(((b & 0x80u) << 24) | ((b & 0x7fu) << 20)) * 0x1p120f;
}

// decode 8 fp8 + BN + ReLU -> 8 bf16 packed in uint4 (zero if !valid)
__device__ __forceinline__ uint4 stage8(uint2 raw, const float* __restrict__ sc,
                                        const float* __restrict__ sh, int c0, bool valid) {
  unsigned short o[8];
#pragma unroll
  for (int j = 0; j < 8; ++j) {
    float f = 0.f;
    if (valid) {
      unsigned byte = ((j < 4 ? raw.x : raw.y) >> (8 * (j & 3))) & 0xffu;
      f = fmaxf(fp82f(byte) * sc[c0 + j] + sh[c0 + j], 0.f);
    }
    o[j] = f2bf(f);
  }
  return make_uint4((unsigned)o[0] | ((unsigned)o[1] << 16),
                    (unsigned)o[2] | ((unsigned)o[3] << 16),
                    (unsigned)o[4] | ((unsigned)o[5] << 16),
                    (unsigned)o[6] | ((unsigned)o[7] << 16));
}

// ---------------- weight prepack: per-(K-step, colgroup) 1KB fragment blobs ----
// blob unit: [step][og][lane(64)][j(8)] bf16; lane=(cin>>3 &3)*16 + (o&15), j=cin&7
__global__ void prepack_w2_kernel(const float* __restrict__ w2, uint8_t* __restrict__ wp) {
  int i = blockIdx.x * 256 + threadIdx.x;
  if (i >= 163840) return;
  int t = i % 5, oc = i / 5;
  int cin = oc & 127, o = oc >> 7;
  int step = t * 4 + (cin >> 5);
  int og = o >> 4;
  int lane = ((cin >> 3) & 3) * 16 + (o & 15);
  int j = cin & 7;
  *(unsigned short*)(wp + ((size_t)(step * 16 + og) << 10) + lane * 16 + j * 2) = f2bf(w2[i]);
}
__global__ void prepack_w3_kernel(const float* __restrict__ w3, uint8_t* __restrict__ wp) {
  int i = blockIdx.x * 256 + threadIdx.x;
  if (i >= 98304) return;
  int t = i % 3, oc = i / 3;
  int cin = oc & 255, o = oc >> 8;
  int step = t * 8 + (cin >> 5);
  int og = o >> 4;
  int lane = ((cin >> 3) & 3) * 16 + (o & 15);
  int j = cin & 7;
  *(unsigned short*)(wp + ((size_t)(step * 8 + og) << 10) + lane * 16 + j * 2) = f2bf(w3[i]);
}

__global__ void prep_nalu_kernel(const float* __restrict__ wh1, const float* __restrict__ mh1,
                                 const float* __restrict__ wh2, const float* __restrict__ mh2,
                                 float* __restrict__ W1, float* __restrict__ W2) {
  int i = blockIdx.x * 256 + threadIdx.x;
  if (i < 16384) {
    W1[i] = tanhf(wh1[i]) * (1.0f / (1.0f + expf(-mh1[i])));
  } else if (i < 18432) {
    int k = i - 16384;
    W2[k] = tanhf(wh2[k]) * (1.0f / (1.0f + expf(-mh2[k])));
  }
}

// ---------------- conv1: C_in=1, k=8 fp32 vector -> y1 fp8 + stats --------------
__global__ __launch_bounds__(256) void conv1_kernel(const float* __restrict__ inp,
                                                    const float* __restrict__ w1,
                                                    uint8_t* __restrict__ y1,
                                                    float* __restrict__ partials) {
  __shared__ float xsh[272];
  __shared__ float reds[2][8][128];
  const int tid = threadIdx.x;
  const int b = blockIdx.y;
  const int l0 = blockIdx.x * 256;
  const float* xb = inp + (size_t)b * 4096;
  for (int j = tid; j < 263; j += 256) {
    int li = l0 - 4 + j;
    xsh[j] = ((unsigned)li < 4096u) ? xb[li] : 0.f;
  }
  __syncthreads();
  const int cg = tid & 31, lsub = tid >> 5;
  float w[4][8];
#pragma unroll
  for (int ci = 0; ci < 4; ++ci)
#pragma unroll
    for (int t = 0; t < 8; ++t) w[ci][t] = w1[(cg * 4 + ci) * 8 + t];
  float s[4] = {0.f, 0.f, 0.f, 0.f}, q[4] = {0.f, 0.f, 0.f, 0.f};
  uint8_t* yb = y1 + ((size_t)b * LROWS + (ROW0 + l0)) * 128;
  for (int li = lsub; li < 256; li += 8) {
    if (l0 + li >= NVALID) break;
    unsigned pk = 0;
#pragma unroll
    for (int ci = 0; ci < 4; ++ci) {
      float a = 0.f;
#pragma unroll
      for (int t = 0; t < 8; ++t) a += xsh[li + t] * w[ci][t];
      s[ci] += a;
      q[ci] += a * a;
      pk |= (unsigned)f2fp8(a) << (8 * ci);
    }
    *(unsigned*)(yb + (size_t)li * 128 + cg * 4) = pk;
  }
#pragma unroll
  for (int ci = 0; ci < 4; ++ci) {
    reds[0][lsub][cg * 4 + ci] = s[ci];
    reds[1][lsub][cg * 4 + ci] = q[ci];
  }
  __syncthreads();
  if (tid < 128) {
    float ss = 0.f, qq = 0.f;
#pragma unroll
    for (int g = 0; g < 8; ++g) {
      ss += reds[0][g][tid];
      qq += reds[1][g][tid];
    }
    float* pb = partials + ((size_t)b * 17 + blockIdx.x) * 256;
    pb[tid] = ss;
    pb[128 + tid] = qq;
  }
}

// ---------------- BN finalize ---------------------------------------------------
__global__ __launch_bounds__(256) void finalize_kernel(const float* __restrict__ partials,
                                                       int nblk, int C,
                                                       const float* __restrict__ gamma,
                                                       const float* __restrict__ beta,
                                                       float* __restrict__ scale,
                                                       float* __restrict__ shift) {
  int c = blockIdx.x;
  float s = 0.f, q = 0.f;
  for (int i = threadIdx.x; i < nblk; i += 256) {
    const float* p = partials + (size_t)i * 2 * C;
    s += p[c];
    q += p[C + c];
  }
  __shared__ float rs[256], rq[256];
  rs[threadIdx.x] = s;
  rq[threadIdx.x] = q;
  __syncthreads();
  for (int st = 128; st > 0; st >>= 1) {
    if (threadIdx.x < st) {
      rs[threadIdx.x] += rs[threadIdx.x + st];
      rq[threadIdx.x] += rq[threadIdx.x + st];
    }
    __syncthreads();
  }
  if (threadIdx.x == 0) {
    const float N = 128.0f * 4097.0f;
    float mean = rs[0] / N;
    float var = rq[0] / N - mean * mean;
    float sc = gamma[c] * rsqrtf(var + 1e-5f);
    scale[c] = sc;
    shift[c] = beta[c] - mean * sc;
  }
}

// ---------------- conv2: 128ch -> 256ch, k=5, MFMA bf16 -------------------------
// block: 128 rows x 256 cols, 8 waves (2x4), wave 64x64. X LDS-resident, W from L2.
__global__ __launch_bounds__(512) void conv2_kernel(const uint8_t* __restrict__ y1,
                                                    const uint8_t* __restrict__ wp,
                                                    const float* __restrict__ s1,
                                                    const float* __restrict__ t1,
                                                    uint8_t* __restrict__ y2,
                                                    float* __restrict__ partials) {
  __shared__ uint4 xs4[2112];  // 132 rows x 256B (bf16 x128ch), XOR-swizzled
  uint8_t* xsb = (uint8_t*)xs4;
  const int tid = threadIdx.x;
  const int b = blockIdx.y;
  const int l0 = blockIdx.x * 128;
  {
    const uint8_t* xrow = y1 + ((size_t)b * LROWS + (ROW0 + l0 - 2)) * 128;
    for (int u = tid; u < 2112; u += 512) {
      int row = u >> 4, g8 = u & 15;
      int gl = l0 - 2 + row;
      bool valid = (unsigned)gl < (unsigned)NVALID;
      uint2 raw = *(const uint2*)(xrow + (size_t)row * 128 + g8 * 8);
      uint4 p = stage8(raw, s1, t1, g8 * 8, valid);
      *(uint4*)(xsb + row * 256 + ((g8 * 16) ^ ((row & 7) << 4))) = p;
    }
  }
  __syncthreads();
  const int lane = tid & 63, wid = tid >> 6;
  const int wr = wid >> 2, wc = wid & 3;
  const int lrow = lane & 15, lk = lane >> 4;
  const int r0 = wr * 64, c0 = wc * 64;
  const uint8_t* wpl = wp + ((size_t)(wc * 4) << 10) + (size_t)lane * 16;
  f32x4 acc[4][4] = {};
#pragma unroll
  for (int t = 0; t < 5; ++t) {
    const int swz = ((lrow + t) & 7) << 4;
#pragma unroll
    for (int kk = 0; kk < 4; ++kk) {
      const int kb = (kk * 64 + lk * 16) ^ swz;
      bf16x8 a[4], bb[4];
#pragma unroll
      for (int fr = 0; fr < 4; ++fr)
        a[fr] = *(const bf16x8*)(xsb + (size_t)((r0 + fr * 16 + lrow + t) * 256) + kb);
      const uint8_t* wstep = wpl + (size_t)(t * 4 + kk) * 16384;
#pragma unroll
      for (int fc = 0; fc < 4; ++fc) bb[fc] = *(const bf16x8*)(wstep + fc * 1024);
#pragma unroll
      for (int fr = 0; fr < 4; ++fr)
#pragma unroll
        for (int fc = 0; fc < 4; ++fc)
          acc[fr][fc] = __builtin_amdgcn_mfma_f32_16x16x32_bf16(a[fr], bb[fc], acc[fr][fc], 0, 0, 0);
    }
  }
  __syncthreads();
  // epilogue: fp8 store (masked) + fp32 stats partials
  float ps[4] = {0.f, 0.f, 0.f, 0.f}, pq[4] = {0.f, 0.f, 0.f, 0.f};
  uint8_t* yb = y2 + ((size_t)b * LROWS + (ROW0 + l0)) * 256;
#pragma unroll
  for (int fr = 0; fr < 4; ++fr)
#pragma unroll
    for (int fc = 0; fc < 4; ++fc) {
      int col = c0 + fc * 16 + lrow;
#pragma unroll
      for (int rg = 0; rg < 4; ++rg) {
        int r = r0 + fr * 16 + lk * 4 + rg;
        if (l0 + r < NVALID) {
          float v = acc[fr][fc][rg];
          yb[(size_t)r * 256 + col] = f2fp8(v);
          ps[fc] += v;
          pq[fc] += v * v;
        }
      }
    }
  float* sred = (float*)xs4;  // [wr][{s,q}][256]
#pragma unroll
  for (int fc = 0; fc < 4; ++fc) {
    float s = ps[fc], q = pq[fc];
    s += __shfl_xor(s, 16); s += __shfl_xor(s, 32);
    q += __shfl_xor(q, 16); q += __shfl_xor(q, 32);
    if (lk == 0) {
      int col = c0 + fc * 16 + lrow;
      sred[wr * 512 + col] = s;
      sred[wr * 512 + 256 + col] = q;
    }
  }
  __syncthreads();
  if (tid < 256) {
    float s = sred[tid] + sred[512 + tid];
    float q = sred[256 + tid] + sred[768 + tid];
    float* pb = partials + ((size_t)b * 33 + blockIdx.x) * 512;
    pb[tid] = s;
    pb[256 + tid] = q;
  }
}

// ---------------- conv3: 256ch -> 128ch, k=3, MFMA bf16, 2 channel-halves -------
__global__ __launch_bounds__(512) void conv3_kernel(const uint8_t* __restrict__ y2,
                                                    const uint8_t* __restrict__ wp,
                                                    const float* __restrict__ s2,
                                                    const float* __restrict__ t2,
                                                    uint8_t* __restrict__ y3,
                                                    float* __restrict__ partials) {
  __shared__ uint4 xs4[2080];  // 130 rows x 256B (bf16 x128ch half), swizzled
  uint8_t* xsb = (uint8_t*)xs4;
  const int tid = threadIdx.x;
  const int b = blockIdx.y;
  const int l0 = blockIdx.x * 128;
  const int lane = tid & 63, wid = tid >> 6;
  const int wr = wid >> 2, wc = wid & 3;
  const int lrow = lane & 15, lk = lane >> 4;
  const int r0 = wr * 64, c0 = wc * 32;
  const uint8_t* wpl = wp + ((size_t)(wc * 2) << 10) + (size_t)lane * 16;
  f32x4 acc[4][2] = {};
#pragma unroll 1
  for (int h = 0; h < 2; ++h) {
    {
      const uint8_t* xrow = y2 + ((size_t)b * LROWS + (ROW0 + l0 - 1)) * 256 + h * 128;
      for (int u = tid; u < 2080; u += 512) {
        int row = u >> 4, g8 = u & 15;
        int gl = l0 - 1 + row;
        bool valid = (unsigned)gl < (unsigned)NVALID;
        uint2 raw = *(const uint2*)(xrow + (size_t)row * 256 + g8 * 8);
        uint4 p = stage8(raw, s2, t2, h * 128 + g8 * 8, valid);
        *(uint4*)(xsb + row * 256 + ((g8 * 16) ^ ((row & 7) << 4))) = p;
      }
    }
    __syncthreads();
#pragma unroll
    for (int t = 0; t < 3; ++t) {
      const int swz = ((lrow + t) & 7) << 4;
#pragma unroll
      for (int kk = 0; kk < 4; ++kk) {
        const int kb = (kk * 64 + lk * 16) ^ swz;
        bf16x8 a[4], bb[2];
#pragma unroll
        for (int fr = 0; fr < 4; ++fr)
          a[fr] = *(const bf16x8*)(xsb + (size_t)((r0 + fr * 16 + lrow + t) * 256) + kb);
        const uint8_t* wstep = wpl + (size_t)(t * 8 + h * 4 + kk) * 8192;
#pragma unroll
        for (int fc = 0; fc < 2; ++fc) bb[fc] = *(const bf16x8*)(wstep + fc * 1024);
#pragma unroll
        for (int fr = 0; fr < 4; ++fr)
#pragma unroll
          for (int fc = 0; fc < 2; ++fc)
            acc[fr][fc] = __builtin_amdgcn_mfma_f32_16x16x32_bf16(a[fr], bb[fc], acc[fr][fc], 0, 0, 0);
      }
    }
    __syncthreads();
  }
  float ps[2] = {0.f, 0.f}, pq[2] = {0.f, 0.f};
  uint8_t* yb = y3 + ((size_t)b * LROWS + (ROW0 + l0)) * 128;
#pragma unroll
  for (int fr = 0; fr < 4; ++fr)
#pragma unroll
    for (int fc = 0; fc < 2; ++fc) {
      int col = c0 + fc * 16 + lrow;
#pragma unroll
      for (int rg = 0; rg < 4; ++rg) {
        int r = r0 + fr * 16 + lk * 4 + rg;
        if (l0 + r < NVALID) {
          float v = acc[fr][fc][rg];
          yb[(size_t)r * 128 + col] = f2fp8(v);
          ps[fc] += v;
          pq[fc] += v * v;
        }
      }
    }
  float* sred = (float*)xs4;  // [wr][{s,q}][128]
#pragma unroll
  for (int fc = 0; fc < 2; ++fc) {
    float s = ps[fc], q = pq[fc];
    s += __shfl_xor(s, 16); s += __shfl_xor(s, 32);
    q += __shfl_xor(q, 16); q += __shfl_xor(q, 32);
    if (lk == 0) {
      int col = c0 + fc * 16 + lrow;
      sred[wr * 256 + col] = s;
      sred[wr * 256 + 128 + col] = q;
    }
  }
  __syncthreads();
  if (tid < 128) {
    float s = sred[tid] + sred[256 + tid];
    float q = sred[128 + tid] + sred[384 + tid];
    float* pb = partials + ((size_t)b * 33 + blockIdx.x) * 256;
    pb[tid] = s;
    pb[128 + tid] = q;
  }
}

// ---------------- feat: BN3+ReLU fused into length-mean partials ----------------
__global__ __launch_bounds__(256) void feat_kernel(const uint8_t* __restrict__ y3,
                                                   const float* __restrict__ s3,
                                                   const float* __restrict__ t3,
                                                   float* __restrict__ fpart) {
  const int b = blockIdx.y, chk = blockIdx.x;
  const int cq = threadIdx.x & 31, lg = threadIdx.x >> 5;
  const uint8_t* base = y3 + ((size_t)b * LROWS + ROW0) * 128;
  float sc[4], sh[4], acc[4] = {0.f, 0.f, 0.f, 0.f};
#pragma unroll
  for (int ci = 0; ci < 4; ++ci) {
    sc[ci] = s3[cq * 4 + ci];
    sh[ci] = t3[cq * 4 + ci];
  }
  int lstart = chk * 513, lend = lstart + 513;
  if (lend > NVALID) lend = NVALID;
  for (int l = lstart + lg; l < lend; l += 8) {
    unsigned u = *(const unsigned*)(base + (size_t)l * 128 + cq * 4);
#pragma unroll
    for (int ci = 0; ci < 4; ++ci)
      acc[ci] += fmaxf(fp82f((u >> (8 * ci)) & 0xffu) * sc[ci] + sh[ci], 0.f);
  }
  __shared__ float red[8][128];
#pragma unroll
  for (int ci = 0; ci < 4; ++ci) red[lg][cq * 4 + ci] = acc[ci];
  __syncthreads();
  if (threadIdx.x < 128) {
    float sum = 0.f;
#pragma unroll
    for (int g = 0; g < 8; ++g) sum += red[g][threadIdx.x];
    fpart[((size_t)chk * 128 + b) * 128 + threadIdx.x] = sum;
  }
}

// ---------------- head: NALU x2 + final linear (fp32) ---------------------------
__global__ __launch_bounds__(128) void head_kernel(const float* __restrict__ fpart,
                                                   const float* __restrict__ W1,
                                                   const float* __restrict__ G1,
                                                   const float* __restrict__ W2,
                                                   const float* __restrict__ G2,
                                                   const float* __restrict__ fw,
                                                   const float* __restrict__ fb,
                                                   float* __restrict__ out) {
  const int b = blockIdx.x, j = threadIdx.x;
  __shared__ float xs[128], lxs[128], h1[128], lh1[128], h2[16];
  float x = 0.f;
#pragma unroll
  for (int chk = 0; chk < 8; ++chk) x += fpart[((size_t)chk * 128 + b) * 128 + j];
  x *= (1.0f / 4097.0f);
  xs[j] = x;
  lxs[j] = logf(fabsf(x) + 1e-10f);
  __syncthreads();
  float a = 0.f, me = 0.f, ga = 0.f;
  for (int i = 0; i < 128; ++i) {
    float w = W1[j * 128 + i];
    a += xs[i] * w;
    me += lxs[i] * w;
    ga += xs[i] * G1[j * 128 + i];
  }
  float g = 1.0f / (1.0f + expf(-ga));
  float h = g * a + (1.0f - g) * expf(me);
  h1[j] = h;
  lh1[j] = logf(fabsf(h) + 1e-10f);
  __syncthreads();
  if (j < 16) {
    float a2 = 0.f, m2 = 0.f, g2 = 0.f;
    for (int i = 0; i < 128; ++i) {
      float w = W2[j * 128 + i];
      a2 += h1[i] * w;
      m2 += lh1[i] * w;
      g2 += h1[i] * G2[j * 128 + i];
    }
    float gg = 1.0f / (1.0f + expf(-g2));
    h2[j] = gg * a2 + (1.0f - gg) * expf(m2);
  }
  __syncthreads();
  if (j == 0) {
    float o = fb[0];
#pragma unroll
    for (int i = 0; i < 16; ++i) o += h2[i] * fw[i];
    out[b] = o;
  }
}

// ---------------- launch --------------------------------------------------------
extern "C" void kernel_launch(void* const* d_in, const int* in_sizes, int n_in,
                              void* d_out, int out_size, void* d_ws, size_t ws_size,
                              hipStream_t stream) {
  (void)in_sizes; (void)n_in; (void)out_size; (void)ws_size;
  const float* inp = (const float*)d_in[0];
  const float* w1  = (const float*)d_in[1];
  const float* g1  = (const float*)d_in[3];
  const float* b1  = (const float*)d_in[4];
  const float* w2  = (const float*)d_in[5];
  const float* g2  = (const float*)d_in[7];
  const float* b2  = (const float*)d_in[8];
  const float* w3  = (const float*)d_in[9];
  const float* g3  = (const float*)d_in[11];
  const float* b3  = (const float*)d_in[12];
  const float* wh1 = (const float*)d_in[13];
  const float* mh1 = (const float*)d_in[14];
  const float* G1  = (const float*)d_in[15];
  const float* wh2 = (const float*)d_in[16];
  const float* mh2 = (const float*)d_in[17];
  const float* G2  = (const float*)d_in[18];
  const float* fw  = (const float*)d_in[19];
  const float* fb  = (const float*)d_in[20];
  float* out = (float*)d_out;

  uint8_t* ws = (uint8_t*)d_ws;
  size_t off = 0;
  auto alloc = [&](size_t n) {
    uint8_t* p = ws + off;
    off += (n + 255) & ~(size_t)255;
    return p;
  };
  uint8_t* y1  = alloc((size_t)128 * LROWS * 128);   // fp8; later aliased as y3
  uint8_t* y2  = alloc((size_t)128 * LROWS * 256);   // fp8
  uint8_t* w2p = alloc((size_t)320 * 1024);
  uint8_t* w3p = alloc((size_t)192 * 1024);
  float* part1 = (float*)alloc((size_t)2176 * 256 * 4);
  float* part2 = (float*)alloc((size_t)4224 * 512 * 4);
  float* part3 = (float*)alloc((size_t)4224 * 256 * 4);
  float* s1 = (float*)alloc(128 * 4); float* t1 = (float*)alloc(128 * 4);
  float* s2 = (float*)alloc(256 * 4); float* t2 = (float*)alloc(256 * 4);
  float* s3 = (float*)alloc(128 * 4); float* t3 = (float*)alloc(128 * 4);
  float* fpart = (float*)alloc((size_t)8 * 128 * 128 * 4);
  float* W1n = (float*)alloc(128 * 128 * 4);
  float* W2n = (float*)alloc(16 * 128 * 4);
  uint8_t* y3 = y1;  // alias: y1 dead once conv2 done

  prepack_w2_kernel<<<640, 256, 0, stream>>>(w2, w2p);
  prepack_w3_kernel<<<384, 256, 0, stream>>>(w3, w3p);
  prep_nalu_kernel<<<72, 256, 0, stream>>>(wh1, mh1, wh2, mh2, W1n, W2n);

  conv1_kernel<<<dim3(17, 128), 256, 0, stream>>>(inp, w1, y1, part1);
  finalize_kernel<<<128, 256, 0, stream>>>(part1, 2176, 128, g1, b1, s1, t1);

  conv2_kernel<<<dim3(33, 128), 512, 0, stream>>>(y1, w2p, s1, t1, y2, part2);
  finalize_kernel<<<256, 256, 0, stream>>>(part2, 4224, 256, g2, b2, s2, t2);

  conv3_kernel<<<dim3(33, 128), 512, 0, stream>>>(y2, w3p, s2, t2, y3, part3);
  finalize_kernel<<<128, 256, 0, stream>>>(part3, 4224, 128, g3, b3, s3, t3);

  feat_kernel<<<dim3(8, 128), 256, 0, stream>>>(y3, s3, t3, fpart);
  head_kernel<<<128, 128, 0, stream>>>(fpart, W1n, G1, W2n, G2, fw, fb, out);
}

// Round 4
// 1146.754 us; speedup vs baseline: 1.0417x; 1.0417x over previous
//
#include <hip/hip_runtime.h>
#include <stdint.h>

#define LROWS 4240
#define ROW0 8
#define NVALID 4097

typedef float f32x4 __attribute__((ext_vector_type(4)));
typedef short bf16x8 __attribute__((ext_vector_type(8)));

__device__ __forceinline__ unsigned short f2bf(float f) {
  unsigned u = __float_as_uint(f);
  u += 0x7fffu + ((u >> 16) & 1u);
  return (unsigned short)(u >> 16);
}
__device__ __forceinline__ float bf2f(unsigned short h) {
  return __uint_as_float(((unsigned)h) << 16);
}
// OCP e4m3fn codec via exponent-shift trick (exact, incl. subnormals, RNE)
__device__ __forceinline__ uint8_t f2fp8(float f) {
  f = fminf(fmaxf(f, -448.f), 448.f);
  unsigned u = __float_as_uint(f * 0x1p-120f);
  unsigned s = (u >> 24) & 0x80u;
  u &= 0x7fffffffu;
  u += 0x7ffffu + ((u >> 20) & 1u);
  return (uint8_t)(s | (u >> 20));
}
__device__ __forceinline__ float fp82f(unsigned b) {
  return __uint_as_float(((b & 0x80u) << 24) | ((b & 0x7fu) << 20)) * 0x1p120f;
}

// decode 8 fp8 + BN + ReLU -> 8 bf16 packed in uint4 (zero if !valid)
__device__ __forceinline__ uint4 stage8(uint2 raw, const float* __restrict__ sc,
                                        const float* __restrict__ sh, int c0, bool valid) {
  unsigned short o[8];
#pragma unroll
  for (int j = 0; j < 8; ++j) {
    float f = 0.f;
    if (valid) {
      unsigned byte = ((j < 4 ? raw.x : raw.y) >> (8 * (j & 3))) & 0xffu;
      f = fmaxf(fp82f(byte) * sc[c0 + j] + sh[c0 + j], 0.f);
    }
    o[j] = f2bf(f);
  }
  return make_uint4((unsigned)o[0] | ((unsigned)o[1] << 16),
                    (unsigned)o[2] | ((unsigned)o[3] << 16),
                    (unsigned)o[4] | ((unsigned)o[5] << 16),
                    (unsigned)o[6] | ((unsigned)o[7] << 16));
}

// ---------------- weight prepack: per-(K-step, colgroup) 1KB fragment blobs ----
__global__ void prepack_w2_kernel(const float* __restrict__ w2, uint8_t* __restrict__ wp) {
  int i = blockIdx.x * 256 + threadIdx.x;
  if (i >= 163840) return;
  int t = i % 5, oc = i / 5;
  int cin = oc & 127, o = oc >> 7;
  int step = t * 4 + (cin >> 5);
  int og = o >> 4;
  int lane = ((cin >> 3) & 3) * 16 + (o & 15);
  int j = cin & 7;
  *(unsigned short*)(wp + ((size_t)(step * 16 + og) << 10) + lane * 16 + j * 2) = f2bf(w2[i]);
}
__global__ void prepack_w3_kernel(const float* __restrict__ w3, uint8_t* __restrict__ wp) {
  int i = blockIdx.x * 256 + threadIdx.x;
  if (i >= 98304) return;
  int t = i % 3, oc = i / 3;
  int cin = oc & 255, o = oc >> 8;
  int step = t * 8 + (cin >> 5);
  int og = o >> 4;
  int lane = ((cin >> 3) & 3) * 16 + (o & 15);
  int j = cin & 7;
  *(unsigned short*)(wp + ((size_t)(step * 8 + og) << 10) + lane * 16 + j * 2) = f2bf(w3[i]);
}

__global__ void prep_nalu_kernel(const float* __restrict__ wh1, const float* __restrict__ mh1,
                                 const float* __restrict__ wh2, const float* __restrict__ mh2,
                                 float* __restrict__ W1, float* __restrict__ W2) {
  int i = blockIdx.x * 256 + threadIdx.x;
  if (i < 16384) {
    W1[i] = tanhf(wh1[i]) * (1.0f / (1.0f + expf(-mh1[i])));
  } else if (i < 18432) {
    int k = i - 16384;
    W2[k] = tanhf(wh2[k]) * (1.0f / (1.0f + expf(-mh2[k])));
  }
}

// ---------------- conv1: C_in=1, k=8 fp32 vector -> y1 fp8 + stats --------------
__global__ __launch_bounds__(256) void conv1_kernel(const float* __restrict__ inp,
                                                    const float* __restrict__ w1,
                                                    uint8_t* __restrict__ y1,
                                                    float* __restrict__ partials) {
  __shared__ float xsh[272];
  __shared__ float reds[2][8][128];
  const int tid = threadIdx.x;
  const int b = blockIdx.y;
  const int l0 = blockIdx.x * 256;
  const float* xb = inp + (size_t)b * 4096;
  for (int j = tid; j < 263; j += 256) {
    int li = l0 - 4 + j;
    xsh[j] = ((unsigned)li < 4096u) ? xb[li] : 0.f;
  }
  __syncthreads();
  const int cg = tid & 31, lsub = tid >> 5;
  float w[4][8];
#pragma unroll
  for (int ci = 0; ci < 4; ++ci)
#pragma unroll
    for (int t = 0; t < 8; ++t) w[ci][t] = w1[(cg * 4 + ci) * 8 + t];
  float s[4] = {0.f, 0.f, 0.f, 0.f}, q[4] = {0.f, 0.f, 0.f, 0.f};
  uint8_t* yb = y1 + ((size_t)b * LROWS + (ROW0 + l0)) * 128;
  for (int li = lsub; li < 256; li += 8) {
    if (l0 + li >= NVALID) break;
    unsigned pk = 0;
#pragma unroll
    for (int ci = 0; ci < 4; ++ci) {
      float a = 0.f;
#pragma unroll
      for (int t = 0; t < 8; ++t) a += xsh[li + t] * w[ci][t];
      s[ci] += a;
      q[ci] += a * a;
      pk |= (unsigned)f2fp8(a) << (8 * ci);
    }
    *(unsigned*)(yb + (size_t)li * 128 + cg * 4) = pk;
  }
#pragma unroll
  for (int ci = 0; ci < 4; ++ci) {
    reds[0][lsub][cg * 4 + ci] = s[ci];
    reds[1][lsub][cg * 4 + ci] = q[ci];
  }
  __syncthreads();
  if (tid < 128) {
    float ss = 0.f, qq = 0.f;
#pragma unroll
    for (int g = 0; g < 8; ++g) {
      ss += reds[0][g][tid];
      qq += reds[1][g][tid];
    }
    float* pb = partials + ((size_t)b * 17 + blockIdx.x) * 256;
    pb[tid] = ss;
    pb[128 + tid] = qq;
  }
}

// ---------------- BN finalize ---------------------------------------------------
__global__ __launch_bounds__(256) void finalize_kernel(const float* __restrict__ partials,
                                                       int nblk, int C,
                                                       const float* __restrict__ gamma,
                                                       const float* __restrict__ beta,
                                                       float* __restrict__ scale,
                                                       float* __restrict__ shift) {
  int c = blockIdx.x;
  float s = 0.f, q = 0.f;
  for (int i = threadIdx.x; i < nblk; i += 256) {
    const float* p = partials + (size_t)i * 2 * C;
    s += p[c];
    q += p[C + c];
  }
  __shared__ float rs[256], rq[256];
  rs[threadIdx.x] = s;
  rq[threadIdx.x] = q;
  __syncthreads();
  for (int st = 128; st > 0; st >>= 1) {
    if (threadIdx.x < st) {
      rs[threadIdx.x] += rs[threadIdx.x + st];
      rq[threadIdx.x] += rq[threadIdx.x + st];
    }
    __syncthreads();
  }
  if (threadIdx.x == 0) {
    const float N = 128.0f * 4097.0f;
    float mean = rs[0] / N;
    float var = rq[0] / N - mean * mean;
    float sc = gamma[c] * rsqrtf(var + 1e-5f);
    scale[c] = sc;
    shift[c] = beta[c] - mean * sc;
  }
}

// shared A-fragment loader (LDS row stride 256B, steps = t*4+kk)
#define LOADA(S, D)                                                         \
  {                                                                         \
    const int t_ = (S) >> 2, kk_ = (S) & 3;                                 \
    const int sw_ = ((lrow + t_) & 7) << 4;                                 \
    const int kb_ = (kk_ * 64 + lk * 16) ^ sw_;                             \
    D[0] = *(const bf16x8*)(abase[0] + t_ * 256 + kb_);                     \
    D[1] = *(const bf16x8*)(abase[1] + t_ * 256 + kb_);                     \
    D[2] = *(const bf16x8*)(abase[2] + t_ * 256 + kb_);                     \
    D[3] = *(const bf16x8*)(abase[3] + t_ * 256 + kb_);                     \
  }

// ---------------- conv2: 128ch -> 256ch, k=5, MFMA bf16, pipelined --------------
// block 128x256, 8 waves (2x4), wave 64x64. A dist-1 (LDS), B dist-2 (L2).
__global__ __launch_bounds__(512, 2) void conv2_kernel(const uint8_t* __restrict__ y1,
                                                       const uint8_t* __restrict__ wp,
                                                       const float* __restrict__ s1,
                                                       const float* __restrict__ t1,
                                                       uint8_t* __restrict__ y2,
                                                       float* __restrict__ partials) {
  __shared__ uint4 xs4[2112];  // 132 rows x 256B, XOR-swizzled
  __shared__ float sred[4][256];
  uint8_t* xsb = (uint8_t*)xs4;
  const int tid = threadIdx.x;
  const int b = blockIdx.y;
  const int l0 = blockIdx.x * 128;
  {
    const uint8_t* xrow = y1 + ((size_t)b * LROWS + (ROW0 + l0 - 2)) * 128;
    uint2 raw[5];
#pragma unroll
    for (int it = 0; it < 5; ++it) {
      int u = tid + it * 512;
      if (u < 2112) raw[it] = *(const uint2*)(xrow + (size_t)(u >> 4) * 128 + (u & 15) * 8);
    }
#pragma unroll
    for (int it = 0; it < 5; ++it) {
      int u = tid + it * 512;
      if (u < 2112) {
        int row = u >> 4, g8 = u & 15;
        bool valid = (unsigned)(l0 - 2 + row) < (unsigned)NVALID;
        uint4 p = stage8(raw[it], s1, t1, g8 * 8, valid);
        *(uint4*)(xsb + row * 256 + ((g8 * 16) ^ ((row & 7) << 4))) = p;
      }
    }
  }
  __syncthreads();
  const int lane = tid & 63, wid = tid >> 6;
  const int wr = wid >> 2, wc = wid & 3;
  const int lrow = lane & 15, lk = lane >> 4;
  const int r0 = wr * 64, c0 = wc * 64;
  const uint8_t* wpl = wp + ((size_t)(wc * 4) << 10) + (size_t)lane * 16;
  const uint8_t* abase[4];
#pragma unroll
  for (int fr = 0; fr < 4; ++fr) abase[fr] = xsb + (r0 + fr * 16 + lrow) * 256;
  f32x4 acc[4][4] = {};
  bf16x8 Ar[2][4], Br[3][4];
#define LOADB2(S, D)                                                        \
  {                                                                         \
    const uint8_t* w_ = wpl + (size_t)(S) * 16384;                          \
    D[0] = *(const bf16x8*)(w_);                                            \
    D[1] = *(const bf16x8*)(w_ + 1024);                                     \
    D[2] = *(const bf16x8*)(w_ + 2048);                                     \
    D[3] = *(const bf16x8*)(w_ + 3072);                                     \
  }
  LOADA(0, Ar[0]);
  LOADB2(0, Br[0]);
  LOADB2(1, Br[1]);
#pragma unroll
  for (int s = 0; s < 20; ++s) {
    if (s < 19) LOADA(s + 1, Ar[(s + 1) & 1]);
    if (s < 18) LOADB2(s + 2, Br[(s + 2) % 3]);
#pragma unroll
    for (int fr = 0; fr < 4; ++fr)
#pragma unroll
      for (int fc = 0; fc < 4; ++fc)
        acc[fr][fc] = __builtin_amdgcn_mfma_f32_16x16x32_bf16(Ar[s & 1][fr], Br[s % 3][fc],
                                                              acc[fr][fc], 0, 0, 0);
  }
  __syncthreads();  // X LDS dead -> reuse as output staging
  float ps[4] = {0.f, 0.f, 0.f, 0.f}, pq[4] = {0.f, 0.f, 0.f, 0.f};
#pragma unroll
  for (int fr = 0; fr < 4; ++fr)
#pragma unroll
    for (int fc = 0; fc < 4; ++fc) {
      int col = c0 + fc * 16 + lrow;
#pragma unroll
      for (int rg = 0; rg < 4; ++rg) {
        int r = r0 + fr * 16 + lk * 4 + rg;
        float v = acc[fr][fc][rg];
        xsb[r * 256 + col] = f2fp8(v);
        if (l0 + r < NVALID) {
          ps[fc] += v;
          pq[fc] += v * v;
        }
      }
    }
#pragma unroll
  for (int fc = 0; fc < 4; ++fc) {
    float s = ps[fc], q = pq[fc];
    s += __shfl_xor(s, 16); s += __shfl_xor(s, 32);
    q += __shfl_xor(q, 16); q += __shfl_xor(q, 32);
    if (lk == 0) {
      int col = c0 + fc * 16 + lrow;
      sred[wr * 2 + 0][col] = s;
      sred[wr * 2 + 1][col] = q;
    }
  }
  __syncthreads();
  {
    uint8_t* yb = y2 + ((size_t)b * LROWS + (ROW0 + l0)) * 256;
    int row = tid >> 2, q = tid & 3;
    const uint8_t* src = xsb + row * 256 + q * 64;
    uint8_t* dst = yb + (size_t)row * 256 + q * 64;
    uint4 v0 = *(const uint4*)(src);
    uint4 v1 = *(const uint4*)(src + 16);
    uint4 v2 = *(const uint4*)(src + 32);
    uint4 v3 = *(const uint4*)(src + 48);
    *(uint4*)(dst) = v0;
    *(uint4*)(dst + 16) = v1;
    *(uint4*)(dst + 32) = v2;
    *(uint4*)(dst + 48) = v3;
  }
  if (tid < 256) {
    float* pb = partials + ((size_t)b * 33 + blockIdx.x) * 512;
    pb[tid] = sred[0][tid] + sred[2][tid];
    pb[256 + tid] = sred[1][tid] + sred[3][tid];
  }
}

// ---------------- conv3: 256ch -> 128ch, k=3, MFMA bf16, pipelined --------------
// block 128x128, 8 waves (2x4), wave 64x32; two 128-ch halves; h1 loads early.
__global__ __launch_bounds__(512, 3) void conv3_kernel(const uint8_t* __restrict__ y2,
                                                       const uint8_t* __restrict__ wp,
                                                       const float* __restrict__ s2,
                                                       const float* __restrict__ t2,
                                                       uint8_t* __restrict__ y3,
                                                       float* __restrict__ partials) {
  __shared__ uint4 xs4[2080];  // 130 rows x 256B, XOR-swizzled
  __shared__ float sred[4][128];
  uint8_t* xsb = (uint8_t*)xs4;
  const int tid = threadIdx.x;
  const int b = blockIdx.y;
  const int l0 = blockIdx.x * 128;
  const int lane = tid & 63, wid = tid >> 6;
  const int wr = wid >> 2, wc = wid & 3;
  const int lrow = lane & 15, lk = lane >> 4;
  const int r0 = wr * 64, c0 = wc * 32;
  const uint8_t* wpl = wp + ((size_t)(wc * 2) << 10) + (size_t)lane * 16;
  const uint8_t* xrowbase = y2 + ((size_t)b * LROWS + (ROW0 + l0 - 1)) * 256;
  const uint8_t* abase[4];
#pragma unroll
  for (int fr = 0; fr < 4; ++fr) abase[fr] = xsb + (r0 + fr * 16 + lrow) * 256;
  f32x4 acc[4][2] = {};
  uint2 raw[5];
  // ---- stage half 0
#pragma unroll
  for (int it = 0; it < 5; ++it) {
    int u = tid + it * 512;
    if (u < 2080) raw[it] = *(const uint2*)(xrowbase + (size_t)(u >> 4) * 256 + (u & 15) * 8);
  }
#pragma unroll
  for (int it = 0; it < 5; ++it) {
    int u = tid + it * 512;
    if (u < 2080) {
      int row = u >> 4, g8 = u & 15;
      bool valid = (unsigned)(l0 - 1 + row) < (unsigned)NVALID;
      uint4 p = stage8(raw[it], s2, t2, g8 * 8, valid);
      *(uint4*)(xsb + row * 256 + ((g8 * 16) ^ ((row & 7) << 4))) = p;
    }
  }
  __syncthreads();
  // ---- issue half-1 global loads early (latency hides under half-0 MFMAs)
#pragma unroll
  for (int it = 0; it < 5; ++it) {
    int u = tid + it * 512;
    if (u < 2080) raw[it] = *(const uint2*)(xrowbase + (size_t)(u >> 4) * 256 + 128 + (u & 15) * 8);
  }
#define LOADB3(H, S, D)                                                        \
  {                                                                            \
    const uint8_t* w_ = wpl + (size_t)((((S) >> 2) * 8 + (H) * 4 + ((S) & 3))) * 8192; \
    D[0] = *(const bf16x8*)(w_);                                               \
    D[1] = *(const bf16x8*)(w_ + 1024);                                        \
  }
#define KHALF(H)                                                               \
  {                                                                            \
    bf16x8 Ar[2][4], Br[3][2];                                                 \
    LOADA(0, Ar[0]);                                                           \
    LOADB3(H, 0, Br[0]);                                                       \
    LOADB3(H, 1, Br[1]);                                                       \
    _Pragma("unroll") for (int s = 0; s < 12; ++s) {                           \
      if (s < 11) LOADA(s + 1, Ar[(s + 1) & 1]);                               \
      if (s < 10) LOADB3(H, s + 2, Br[(s + 2) % 3]);                           \
      _Pragma("unroll") for (int fr = 0; fr < 4; ++fr)                         \
          _Pragma("unroll") for (int fc = 0; fc < 2; ++fc)                     \
              acc[fr][fc] = __builtin_amdgcn_mfma_f32_16x16x32_bf16(           \
                  Ar[s & 1][fr], Br[s % 3][fc], acc[fr][fc], 0, 0, 0);         \
    }                                                                          \
  }
  KHALF(0);
  __syncthreads();
  // ---- decode + write half 1
#pragma unroll
  for (int it = 0; it < 5; ++it) {
    int u = tid + it * 512;
    if (u < 2080) {
      int row = u >> 4, g8 = u & 15;
      bool valid = (unsigned)(l0 - 1 + row) < (unsigned)NVALID;
      uint4 p = stage8(raw[it], s2, t2, 128 + g8 * 8, valid);
      *(uint4*)(xsb + row * 256 + ((g8 * 16) ^ ((row & 7) << 4))) = p;
    }
  }
  __syncthreads();
  KHALF(1);
  __syncthreads();  // X LDS dead -> reuse as output staging
  float ps[2] = {0.f, 0.f}, pq[2] = {0.f, 0.f};
#pragma unroll
  for (int fr = 0; fr < 4; ++fr)
#pragma unroll
    for (int fc = 0; fc < 2; ++fc) {
      int col = c0 + fc * 16 + lrow;
#pragma unroll
      for (int rg = 0; rg < 4; ++rg) {
        int r = r0 + fr * 16 + lk * 4 + rg;
        float v = acc[fr][fc][rg];
        xsb[r * 128 + col] = f2fp8(v);
        if (l0 + r < NVALID) {
          ps[fc] += v;
          pq[fc] += v * v;
        }
      }
    }
#pragma unroll
  for (int fc = 0; fc < 2; ++fc) {
    float s = ps[fc], q = pq[fc];
    s += __shfl_xor(s, 16); s += __shfl_xor(s, 32);
    q += __shfl_xor(q, 16); q += __shfl_xor(q, 32);
    if (lk == 0) {
      int col = c0 + fc * 16 + lrow;
      sred[wr * 2 + 0][col] = s;
      sred[wr * 2 + 1][col] = q;
    }
  }
  __syncthreads();
  {
    uint8_t* yb = y3 + ((size_t)b * LROWS + (ROW0 + l0)) * 128;
    int row = tid >> 2, q = tid & 3;
    const uint8_t* src = xsb + row * 128 + q * 32;
    uint8_t* dst = yb + (size_t)row * 128 + q * 32;
    uint4 v0 = *(const uint4*)(src);
    uint4 v1 = *(const uint4*)(src + 16);
    *(uint4*)(dst) = v0;
    *(uint4*)(dst + 16) = v1;
  }
  if (tid < 128) {
    float* pb = partials + ((size_t)b * 33 + blockIdx.x) * 256;
    pb[tid] = sred[0][tid] + sred[2][tid];
    pb[128 + tid] = sred[1][tid] + sred[3][tid];
  }
}

// ---------------- feat: BN3+ReLU fused into length-mean partials ----------------
__global__ __launch_bounds__(256) void feat_kernel(const uint8_t* __restrict__ y3,
                                                   const float* __restrict__ s3,
                                                   const float* __restrict__ t3,
                                                   float* __restrict__ fpart) {
  const int b = blockIdx.y, chk = blockIdx.x;
  const int cq = threadIdx.x & 31, lg = threadIdx.x >> 5;
  const uint8_t* base = y3 + ((size_t)b * LROWS + ROW0) * 128;
  float sc[4], sh[4], acc[4] = {0.f, 0.f, 0.f, 0.f};
#pragma unroll
  for (int ci = 0; ci < 4; ++ci) {
    sc[ci] = s3[cq * 4 + ci];
    sh[ci] = t3[cq * 4 + ci];
  }
  int lstart = chk * 513, lend = lstart + 513;
  if (lend > NVALID) lend = NVALID;
  for (int l = lstart + lg; l < lend; l += 8) {
    unsigned u = *(const unsigned*)(base + (size_t)l * 128 + cq * 4);
#pragma unroll
    for (int ci = 0; ci < 4; ++ci)
      acc[ci] += fmaxf(fp82f((u >> (8 * ci)) & 0xffu) * sc[ci] + sh[ci], 0.f);
  }
  __shared__ float red[8][128];
#pragma unroll
  for (int ci = 0; ci < 4; ++ci) red[lg][cq * 4 + ci] = acc[ci];
  __syncthreads();
  if (threadIdx.x < 128) {
    float sum = 0.f;
#pragma unroll
    for (int g = 0; g < 8; ++g) sum += red[g][threadIdx.x];
    fpart[((size_t)chk * 128 + b) * 128 + threadIdx.x] = sum;
  }
}

// ---------------- head: NALU x2 + final linear (fp32) ---------------------------
__global__ __launch_bounds__(128) void head_kernel(const float* __restrict__ fpart,
                                                   const float* __restrict__ W1,
                                                   const float* __restrict__ G1,
                                                   const float* __restrict__ W2,
                                                   const float* __restrict__ G2,
                                                   const float* __restrict__ fw,
                                                   const float* __restrict__ fb,
                                                   float* __restrict__ out) {
  const int b = blockIdx.x, j = threadIdx.x;
  __shared__ float xs[128], lxs[128], h1[128], lh1[128], h2[16];
  float x = 0.f;
#pragma unroll
  for (int chk = 0; chk < 8; ++chk) x += fpart[((size_t)chk * 128 + b) * 128 + j];
  x *= (1.0f / 4097.0f);
  xs[j] = x;
  lxs[j] = logf(fabsf(x) + 1e-10f);
  __syncthreads();
  float a = 0.f, me = 0.f, ga = 0.f;
  for (int i = 0; i < 128; ++i) {
    float w = W1[j * 128 + i];
    a += xs[i] * w;
    me += lxs[i] * w;
    ga += xs[i] * G1[j * 128 + i];
  }
  float g = 1.0f / (1.0f + expf(-ga));
  float h = g * a + (1.0f - g) * expf(me);
  h1[j] = h;
  lh1[j] = logf(fabsf(h) + 1e-10f);
  __syncthreads();
  if (j < 16) {
    float a2 = 0.f, m2 = 0.f, g2 = 0.f;
    for (int i = 0; i < 128; ++i) {
      float w = W2[j * 128 + i];
      a2 += h1[i] * w;
      m2 += lh1[i] * w;
      g2 += h1[i] * G2[j * 128 + i];
    }
    float gg = 1.0f / (1.0f + expf(-g2));
    h2[j] = gg * a2 + (1.0f - gg) * expf(m2);
  }
  __syncthreads();
  if (j == 0) {
    float o = fb[0];
#pragma unroll
    for (int i = 0; i < 16; ++i) o += h2[i] * fw[i];
    out[b] = o;
  }
}

// ---------------- launch --------------------------------------------------------
extern "C" void kernel_launch(void* const* d_in, const int* in_sizes, int n_in,
                              void* d_out, int out_size, void* d_ws, size_t ws_size,
                              hipStream_t stream) {
  (void)in_sizes; (void)n_in; (void)out_size; (void)ws_size;
  const float* inp = (const float*)d_in[0];
  const float* w1  = (const float*)d_in[1];
  const float* g1  = (const float*)d_in[3];
  const float* b1  = (const float*)d_in[4];
  const float* w2  = (const float*)d_in[5];
  const float* g2  = (const float*)d_in[7];
  const float* b2  = (const float*)d_in[8];
  const float* w3  = (const float*)d_in[9];
  const float* g3  = (const float*)d_in[11];
  const float* b3  = (const float*)d_in[12];
  const float* wh1 = (const float*)d_in[13];
  const float* mh1 = (const float*)d_in[14];
  const float* G1  = (const float*)d_in[15];
  const float* wh2 = (const float*)d_in[16];
  const float* mh2 = (const float*)d_in[17];
  const float* G2  = (const float*)d_in[18];
  const float* fw  = (const float*)d_in[19];
  const float* fb  = (const float*)d_in[20];
  float* out = (float*)d_out;

  uint8_t* ws = (uint8_t*)d_ws;
  size_t off = 0;
  auto alloc = [&](size_t n) {
    uint8_t* p = ws + off;
    off += (n + 255) & ~(size_t)255;
    return p;
  };
  uint8_t* y1  = alloc((size_t)128 * LROWS * 128);   // fp8; later aliased as y3
  uint8_t* y2  = alloc((size_t)128 * LROWS * 256);   // fp8
  uint8_t* w2p = alloc((size_t)320 * 1024);
  uint8_t* w3p = alloc((size_t)192 * 1024);
  float* part1 = (float*)alloc((size_t)2176 * 256 * 4);
  float* part2 = (float*)alloc((size_t)4224 * 512 * 4);
  float* part3 = (float*)alloc((size_t)4224 * 256 * 4);
  float* s1 = (float*)alloc(128 * 4); float* t1 = (float*)alloc(128 * 4);
  float* s2 = (float*)alloc(256 * 4); float* t2 = (float*)alloc(256 * 4);
  float* s3 = (float*)alloc(128 * 4); float* t3 = (float*)alloc(128 * 4);
  float* fpart = (float*)alloc((size_t)8 * 128 * 128 * 4);
  float* W1n = (float*)alloc(128 * 128 * 4);
  float* W2n = (float*)alloc(16 * 128 * 4);
  uint8_t* y3 = y1;  // alias: y1 dead once conv2 done

  prepack_w2_kernel<<<640, 256, 0, stream>>>(w2, w2p);
  prepack_w3_kernel<<<384, 256, 0, stream>>>(w3, w3p);
  prep_nalu_kernel<<<72, 256, 0, stream>>>(wh1, mh1, wh2, mh2, W1n, W2n);

  conv1_kernel<<<dim3(17, 128), 256, 0, stream>>>(inp, w1, y1, part1);
  finalize_kernel<<<128, 256, 0, stream>>>(part1, 2176, 128, g1, b1, s1, t1);

  conv2_kernel<<<dim3(33, 128), 512, 0, stream>>>(y1, w2p, s1, t1, y2, part2);
  finalize_kernel<<<256, 256, 0, stream>>>(part2, 4224, 256, g2, b2, s2, t2);

  conv3_kernel<<<dim3(33, 128), 512, 0, stream>>>(y2, w3p, s2, t2, y3, part3);
  finalize_kernel<<<128, 256, 0, stream>>>(part3, 4224, 128, g3, b3, s3, t3);

  feat_kernel<<<dim3(8, 128), 256, 0, stream>>>(y3, s3, t3, fpart);
  head_kernel<<<128, 128, 0, stream>>>(fpart, W1n, G1, W2n, G2, fw, fb, out);
}